// Round 4
// baseline (443.686 us; speedup 1.0000x reference)
//
#include <hip/hip_runtime.h>

// argmin_c ||x-c|| == argmin_c (||c||^2 - 2 x.c). Cross-term via 3 f16 MFMA
// GEMMs (exact hi/lo split of fp32, lo*lo dropped ~2^-22 rel).
// Round 11: 2-blocks/CU + pinned interleave. Round-10 counters: Occupancy
// 22.7% = ONE 8-wave block/CU (LDS 128KB > 160/2) -> DS-burst and MFMA epochs
// alternate with nothing to fill the gaps; MfmaUtil fell to 41%. Fix:
// 128x128 tile, BK=32, 4 waves, 64KB LDS double buffer -> 2 INDEPENDENT
// blocks/CU (one block's MFMA covers the other's barrier/read epochs).
// Reads pinned one phase ahead of their MFMA consumer via sched_barrier(0)
// separators (compile-time, no runtime cost): counted lgkmcnt instead of
// drain. 2 s_barriers/kt; vmcnt(2) counted, drains only at last kt.
// Accumulation order per acc element unchanged (kt ascending; hh,hl,lh)
// -> bit-identical scores -> identical argmin.
typedef __fp16 f16x2 __attribute__((ext_vector_type(2)));
typedef __fp16 f16x8 __attribute__((ext_vector_type(8)));
typedef float f32x4 __attribute__((ext_vector_type(4)));

constexpr int MM = 32768;   // B*T tokens
constexpr int NN = 2048;    // clusters
constexpr int KK = 768;     // dim
constexpr int NKT = KK / 32;          // 24 k-tiles
constexpr int NA_UNITS = (MM / 16) * NKT;   // 49152 A (mt,kt) wave-tasks
constexpr int NB_UNITS = (NN / 16) * NKT;   //  3072 B (nt,kt) wave-tasks

// Workspace layout (bytes). Apack: [mt][kt][part] 1KB units; Bpack same.
constexpr size_t WS_APACK = 0;
constexpr size_t WS_BPACK = WS_APACK + (size_t)MM * KK * 4;  // 100663296
constexpr size_t WS_CSQ   = WS_BPACK + (size_t)NN * KK * 4;  // 106954752
constexpr size_t WS_SLOT  = WS_CSQ + (size_t)NN * 4;         // 106962944
constexpr size_t WS_NEED  = WS_SLOT + (size_t)MM * 16 * 8;   // 111157248

__device__ __forceinline__ unsigned bc(f16x2 h) {
    return __builtin_bit_cast(unsigned, h);
}

// ---------------- fast path ----------------

// One wave packs one (tile16, ktile32, {hi,lo}) pair: reads 16 rows x 128B of
// fp32, writes two contiguous 1KB units in fragment order
// (byte off = (quad*16 + ln15)*16 holds elements m=ln15, k=quad*8..+7).
// Tail tasks (task >= NA+NB) compute csq: one wave per cluster row.
__global__ __launch_bounds__(256)
void fragpack_kernel(const float* __restrict__ A, const float* __restrict__ Bc,
                     uint4* __restrict__ Ap, uint4* __restrict__ Bp,
                     float* __restrict__ csq) {
    const int task = blockIdx.x * 4 + (threadIdx.x >> 6);
    const int lane = threadIdx.x & 63;

    if (task >= NA_UNITS + NB_UNITS) {          // csq tail: wave-uniform branch
        const int cl = task - (NA_UNITS + NB_UNITS);
        const float4* row = reinterpret_cast<const float4*>(Bc + (size_t)cl * KK);
        float s = 0.f;
#pragma unroll
        for (int w = 0; w < KK / (4 * 64); ++w) {
            float4 v = row[w * 64 + lane];
            s = fmaf(v.x, v.x, s); s = fmaf(v.y, v.y, s);
            s = fmaf(v.z, v.z, s); s = fmaf(v.w, v.w, s);
        }
#pragma unroll
        for (int off = 32; off > 0; off >>= 1) s += __shfl_xor(s, off, 64);
        if (lane == 0) csq[cl] = s;
        return;
    }

    const int ln15 = lane & 15;
    const int quad = lane >> 4;

    const bool isB = task >= NA_UNITS;
    const int t = isB ? task - NA_UNITS : task;
    const int tile = t / NKT, kt = t % NKT;
    const float* src = (isB ? Bc : A) + (size_t)(tile * 16 + ln15) * KK + kt * 32 + quad * 8;
    uint4* dst = (isB ? Bp : Ap) + (size_t)t * 128 + lane;   // 2 units = 128 uint4

    const float4 v0 = *(const float4*)(src);
    const float4 v1 = *(const float4*)(src + 4);
    f16x2 h0 = __builtin_amdgcn_cvt_pkrtz(v0.x, v0.y);
    f16x2 h1 = __builtin_amdgcn_cvt_pkrtz(v0.z, v0.w);
    f16x2 h2 = __builtin_amdgcn_cvt_pkrtz(v1.x, v1.y);
    f16x2 h3 = __builtin_amdgcn_cvt_pkrtz(v1.z, v1.w);
    f16x2 l0 = __builtin_amdgcn_cvt_pkrtz(v0.x-(float)h0[0], v0.y-(float)h0[1]);
    f16x2 l1 = __builtin_amdgcn_cvt_pkrtz(v0.z-(float)h1[0], v0.w-(float)h1[1]);
    f16x2 l2 = __builtin_amdgcn_cvt_pkrtz(v1.x-(float)h2[0], v1.y-(float)h2[1]);
    f16x2 l3 = __builtin_amdgcn_cvt_pkrtz(v1.z-(float)h3[0], v1.w-(float)h3[1]);
    uint4 hv = {bc(h0), bc(h1), bc(h2), bc(h3)};
    uint4 lv = {bc(l0), bc(l1), bc(l2), bc(l3)};
    dst[0]  = hv;
    dst[64] = lv;
}

__global__ __launch_bounds__(64)
void csq_kernel(const float* __restrict__ cc, float* __restrict__ csq) {
    const int cl = blockIdx.x;
    const int lane = threadIdx.x;
    const float4* row = reinterpret_cast<const float4*>(cc + (size_t)cl * KK);
    float s = 0.f;
#pragma unroll
    for (int w = 0; w < KK / (4 * 64); ++w) {
        float4 v = row[w * 64 + lane];
        s = fmaf(v.x, v.x, s); s = fmaf(v.y, v.y, s);
        s = fmaf(v.z, v.z, s); s = fmaf(v.w, v.w, s);
    }
#pragma unroll
    for (int off = 32; off > 0; off >>= 1) s += __shfl_xor(s, off, 64);
    if (lane == 0) csq[cl] = s;
}

#define MF2(a, b, c) __builtin_amdgcn_mfma_f32_16x16x32_f16(a, b, c, 0, 0, 0)
#define DSB() __builtin_amdgcn_sched_barrier(0)

// gemm: 128x128 tile per 256-thread block (4 waves 2Mx2N, wave tile 64x64).
// LDS per buffer (2048 uint4 = 32KB): A units (mtile*2+part)*64, mtile 0..7;
// B units (16 + ntile*2+part)*64. Buf1 at +2048. Two buffers = 64KB ->
// 2 blocks/CU co-resident.
__global__ __launch_bounds__(256, 2)
void gemm_pack_kernel(const uint4* __restrict__ Ap, const uint4* __restrict__ Bp,
                      const float* __restrict__ csq, uint2* __restrict__ slots) {
    __shared__ uint4 ldsq[4096];   // 64 KiB

    // XCD swizzle (round-7 proven): 16 gx-blocks sharing an A tile land on one
    // XCD consecutively -> A panel (393KB) L2-resident; B streams from L3.
    const int b   = blockIdx.x;           // 0..4095
    const int xcd = b & 7;
    const int s   = b >> 3;               // 0..511
    const int gx  = s & 15;               // n-block 0..15
    const int gy  = xcd + ((s >> 4) << 3);   // m-block 0..255

    const int tid  = threadIdx.x;
    const int lane = tid & 63;
    const int ln15 = lane & 15;
    const int quad = lane >> 4;
    const int wave = tid >> 6;            // 0..3
    const int wm   = wave >> 1;           // 0..1
    const int wn   = wave & 1;            // 0..1
    const int tbase = gy * 128;
    const int cb    = gx * 128;

    // Per-wave staging sources: units u = wave*8 + q, q=0..7 (32 units total).
    // u<16 -> A unit (mtile=u>>1, part=u&1); else B unit.
    const uint4* sp[8];
#pragma unroll
    for (int q = 0; q < 8; ++q) {
        const int u = wave * 8 + q;
        const bool isA = u < 16;
        const int v = isA ? u : u - 16;
        const int tile = (isA ? gy * 8 : gx * 8) + (v >> 1);
        const int part = v & 1;
        sp[q] = (isA ? Ap : Bp) + (size_t)tile * NKT * 128 + part * 64 + lane;
    }

#define STAGE2(kt_, bufq_, q_) {                                              \
    _Pragma("unroll")                                                         \
    for (int qq = (q_); qq < (q_) + 2; ++qq)                                  \
        __builtin_amdgcn_global_load_lds(                                     \
            (const __attribute__((address_space(1))) unsigned int*)(sp[qq] + (kt_) * 128), \
            (__attribute__((address_space(3))) unsigned int*)&ldsq[(bufq_) + (wave * 8 + qq) * 64], \
            16, 0, 0); }

    f32x4 acc[4][4];
#pragma unroll
    for (int i = 0; i < 4; ++i)
#pragma unroll
        for (int j = 0; j < 4; ++j) { f32x4 z = {0.f,0.f,0.f,0.f}; acc[i][j] = z; }

    f16x8 Bh[4], Bl[4];
    f16x8 Ah[2], Al[2];

#define RD_B(bufq_) {                                                         \
    _Pragma("unroll")                                                         \
    for (int j = 0; j < 4; ++j) {                                             \
        const int nu = 16 + (wn * 4 + j) * 2;                                 \
        Bh[j] = *(const f16x8*)&ldsq[(bufq_) + nu * 64 + lane];               \
        Bl[j] = *(const f16x8*)&ldsq[(bufq_) + (nu + 1) * 64 + lane];         \
    } }

#define RD_A(bufq_, i_, s_) {                                                 \
    const int au = (wm * 4 + (i_)) * 2;                                       \
    Ah[s_] = *(const f16x8*)&ldsq[(bufq_) + au * 64 + lane];                  \
    Al[s_] = *(const f16x8*)&ldsq[(bufq_) + (au + 1) * 64 + lane]; }

#define MFMA_I(i_, s_) {                                                      \
    __builtin_amdgcn_s_setprio(1);                                            \
    _Pragma("unroll")                                                         \
    for (int j = 0; j < 4; ++j) {                                             \
        acc[i_][j] = MF2(Ah[s_], Bh[j], acc[i_][j]);                          \
        acc[i_][j] = MF2(Ah[s_], Bl[j], acc[i_][j]);                          \
        acc[i_][j] = MF2(Al[s_], Bh[j], acc[i_][j]);                          \
    }                                                                         \
    __builtin_amdgcn_s_setprio(0); }

    // Prologue: stage kt=0 fully into buf0.
    STAGE2(0, 0, 0) STAGE2(0, 0, 2) STAGE2(0, 0, 4) STAGE2(0, 0, 6)

#pragma unroll 1
    for (int kt = 0; kt < NKT; ++kt) {
        const int bufq = (kt & 1) ? 2048 : 0;
        const int nxt  = bufq ^ 2048;
        const bool sn  = (kt + 1 < NKT);

        if (sn) {
            STAGE2(kt + 1, nxt, 0)
            asm volatile("s_waitcnt vmcnt(2)" ::: "memory");
        } else {
            asm volatile("s_waitcnt vmcnt(0)" ::: "memory");
        }
        DSB(); __builtin_amdgcn_s_barrier(); DSB();   // buf[kt] fully staged

        RD_B(bufq)
        RD_A(bufq, 0, 0)
        DSB();
        RD_A(bufq, 1, 1)
        if (sn) STAGE2(kt + 1, nxt, 2)
        DSB();
        MFMA_I(0, 0)
        DSB();
        RD_A(bufq, 2, 0)
        if (sn) STAGE2(kt + 1, nxt, 4)
        DSB();
        MFMA_I(1, 1)
        DSB();
        RD_A(bufq, 3, 1)
        if (sn) STAGE2(kt + 1, nxt, 6)
        DSB();
        MFMA_I(2, 0)
        DSB();
        MFMA_I(3, 1)
        DSB(); __builtin_amdgcn_s_barrier(); DSB();   // release buf[kt]
    }

    // Epilogue: score = csq - 2*dot; C/D layout col=lane&15, row=quad*4+reg.
    float csq4[4];
#pragma unroll
    for (int j = 0; j < 4; ++j) csq4[j] = csq[cb + wn * 64 + j * 16 + ln15];

    float bval[16]; int bidx[16];
#pragma unroll
    for (int i = 0; i < 4; ++i)
#pragma unroll
        for (int r = 0; r < 4; ++r) {
            const int rid = i * 4 + r;
            float bv_ = csq4[0] - 2.0f * acc[i][0][r];
            int   bi_ = cb + wn * 64 + ln15;
#pragma unroll
            for (int j = 1; j < 4; ++j) {
                const float s2 = csq4[j] - 2.0f * acc[i][j][r];
                const int   c = cb + wn * 64 + j * 16 + ln15;
                if (s2 < bv_) { bv_ = s2; bi_ = c; }   // ascending c, strict <
            }
            bval[rid] = bv_; bidx[rid] = bi_;
        }
#pragma unroll
    for (int off = 1; off < 16; off <<= 1) {
#pragma unroll
        for (int rid = 0; rid < 16; ++rid) {
            const float ov = __shfl_xor(bval[rid], off, 64);
            const int   oi = __shfl_xor(bidx[rid], off, 64);
            if (ov < bval[rid] || (ov == bval[rid] && oi < bidx[rid])) {
                bval[rid] = ov; bidx[rid] = oi;
            }
        }
    }

    __syncthreads();                       // all LDS reads done; reuse for tabs
    float* vtab = (float*)&ldsq[0];        // [128 rows][2 wn]
    int*   itab = (int*)&ldsq[64];
    if (ln15 == 0) {
#pragma unroll
        for (int i = 0; i < 4; ++i)
#pragma unroll
            for (int r = 0; r < 4; ++r) {
                const int row = wm * 64 + i * 16 + quad * 4 + r;
                vtab[row * 2 + wn] = bval[i * 4 + r];
                itab[row * 2 + wn] = bidx[i * 4 + r];
            }
    }
    __syncthreads();
    if (tid < 128) {
        float v0 = vtab[tid * 2]; int i0 = itab[tid * 2];
        const float v1 = vtab[tid * 2 + 1]; const int i1 = itab[tid * 2 + 1];
        if (v1 < v0 || (v1 == v0 && i1 < i0)) { v0 = v1; i0 = i1; }
        uint2 e; e.x = __float_as_uint(v0); e.y = (unsigned)i0;
        slots[(size_t)(tbase + tid) * 16 + gx] = e;
    }
}

__global__ __launch_bounds__(256)
void slot_reduce_kernel(const uint2* __restrict__ slots, int* __restrict__ out) {
    const int t = blockIdx.x * 256 + threadIdx.x;
    const uint2* s = slots + (size_t)t * 16;
    float bv = __uint_as_float(s[0].x); int bi = (int)s[0].y;
#pragma unroll
    for (int j = 1; j < 16; ++j) {
        const uint2 e = s[j];
        const float v = __uint_as_float(e.x);
        if (v < bv || (v == bv && (int)e.y < bi)) { bv = v; bi = (int)e.y; }
    }
    out[t] = bi;
}

// ---------------- round-3 fallback (proven, used only if ws too small) ------

__global__ __launch_bounds__(256)
void init_ws_kernel(unsigned long long* __restrict__ w) {
    w[blockIdx.x * 256 + threadIdx.x] = 0xFFFFFFFFFFFFFFFFull;
}

__global__ __launch_bounds__(256, 2)
void argmin_mfma_kernel(const float* __restrict__ A, const float* __restrict__ Bc,
                        const float* __restrict__ csq,
                        unsigned long long* __restrict__ ws64) {
    __shared__ unsigned lds[4 * 128 * 20];
    constexpr int AH = 0, AL = 2560, BH = 5120;

    const int tid  = threadIdx.x;
    const int lane = tid & 63;
    const int ln15 = lane & 15;
    const int quad = lane >> 4;
    const int wave = tid >> 6;
    const int wm = wave >> 1, wn = wave & 1;
    const int tbase = blockIdx.x * 128;
    const int cb    = blockIdx.y * 128;

    const int sr  = tid >> 1;
    const int skh = tid & 1;
    const float* gA = A  + (size_t)(tbase + sr) * KK + skh * 16;
    const float* gB = Bc + (size_t)(cb   + sr) * KK + skh * 16;
    const int wword = sr * 20 + skh * 8;

    f32x4 acc[4][4];
#pragma unroll
    for (int i = 0; i < 4; ++i)
#pragma unroll
        for (int j = 0; j < 4; ++j) { f32x4 z = {0.f,0.f,0.f,0.f}; acc[i][j] = z; }

    float4 av[4], bv[4];
#pragma unroll
    for (int p = 0; p < 4; ++p) {
        av[p] = *(const float4*)(gA + p * 4);
        bv[p] = *(const float4*)(gB + p * 4);
    }

    int aw[4], bw[4];
#pragma unroll
    for (int i = 0; i < 4; ++i) {
        aw[i] = AH + (wm * 64 + i * 16 + ln15) * 20 + quad * 4;
        bw[i] = BH + (wn * 64 + i * 16 + ln15) * 20 + quad * 4;
    }

    for (int k0 = 0; k0 < KK; k0 += 32) {
        __syncthreads();
#pragma unroll
        for (int h = 0; h < 2; ++h) {
            float4 v0 = av[2*h], v1 = av[2*h+1];
            f16x2 h00 = __builtin_amdgcn_cvt_pkrtz(v0.x, v0.y);
            f16x2 h01 = __builtin_amdgcn_cvt_pkrtz(v0.z, v0.w);
            f16x2 h10 = __builtin_amdgcn_cvt_pkrtz(v1.x, v1.y);
            f16x2 h11 = __builtin_amdgcn_cvt_pkrtz(v1.z, v1.w);
            f16x2 l00 = __builtin_amdgcn_cvt_pkrtz(v0.x-(float)h00[0], v0.y-(float)h00[1]);
            f16x2 l01 = __builtin_amdgcn_cvt_pkrtz(v0.z-(float)h01[0], v0.w-(float)h01[1]);
            f16x2 l10 = __builtin_amdgcn_cvt_pkrtz(v1.x-(float)h10[0], v1.y-(float)h10[1]);
            f16x2 l11 = __builtin_amdgcn_cvt_pkrtz(v1.z-(float)h11[0], v1.w-(float)h11[1]);
            uint4 hv = {bc(h00), bc(h01), bc(h10), bc(h11)};
            uint4 lv = {bc(l00), bc(l01), bc(l10), bc(l11)};
            *(uint4*)&lds[AH + wword + 4*h] = hv;
            *(uint4*)&lds[AL + wword + 4*h] = lv;

            float4 w0 = bv[2*h], w1 = bv[2*h+1];
            f16x2 g00 = __builtin_amdgcn_cvt_pkrtz(w0.x, w0.y);
            f16x2 g01 = __builtin_amdgcn_cvt_pkrtz(w0.z, w0.w);
            f16x2 g10 = __builtin_amdgcn_cvt_pkrtz(w1.x, w1.y);
            f16x2 g11 = __builtin_amdgcn_cvt_pkrtz(w1.z, w1.w);
            f16x2 m00 = __builtin_amdgcn_cvt_pkrtz(w0.x-(float)g00[0], w0.y-(float)g00[1]);
            f16x2 m01 = __builtin_amdgcn_cvt_pkrtz(w0.z-(float)g01[0], w0.w-(float)g01[1]);
            f16x2 m10 = __builtin_amdgcn_cvt_pkrtz(w1.x-(float)g10[0], w1.y-(float)g10[1]);
            f16x2 m11 = __builtin_amdgcn_cvt_pkrtz(w1.z-(float)g11[0], w1.w-(float)g11[1]);
            uint4 gv = {bc(g00), bc(g01), bc(g10), bc(g11)};
            uint4 mv = {bc(m00), bc(m01), bc(m10), bc(m11)};
            *(uint4*)&lds[BH + wword + 4*h]        = gv;
            *(uint4*)&lds[BH + 2560 + wword + 4*h] = mv;
        }
        __syncthreads();

        const int kn = k0 + 32;
        if (kn < KK) {
#pragma unroll
            for (int p = 0; p < 4; ++p) {
                av[p] = *(const float4*)(gA + kn + p * 4);
                bv[p] = *(const float4*)(gB + kn + p * 4);
            }
        }

        f16x8 a_h[4], a_l[4], b_h[4], b_l[4];
#pragma unroll
        for (int i = 0; i < 4; ++i) {
            a_h[i] = *(const f16x8*)&lds[aw[i]];
            a_l[i] = *(const f16x8*)&lds[aw[i] + 2560];
            b_h[i] = *(const f16x8*)&lds[bw[i]];
            b_l[i] = *(const f16x8*)&lds[bw[i] + 2560];
        }
#pragma unroll
        for (int i = 0; i < 4; ++i)
#pragma unroll
            for (int j = 0; j < 4; ++j) {
                acc[i][j] = __builtin_amdgcn_mfma_f32_16x16x32_f16(a_h[i], b_h[j], acc[i][j], 0, 0, 0);
                acc[i][j] = __builtin_amdgcn_mfma_f32_16x16x32_f16(a_h[i], b_l[j], acc[i][j], 0, 0, 0);
                acc[i][j] = __builtin_amdgcn_mfma_f32_16x16x32_f16(a_l[i], b_h[j], acc[i][j], 0, 0, 0);
            }
    }

    float csq4[4];
#pragma unroll
    for (int j = 0; j < 4; ++j) csq4[j] = csq[cb + wn * 64 + j * 16 + ln15];

    float bval[16]; int bidx[16];
#pragma unroll
    for (int i = 0; i < 4; ++i)
#pragma unroll
        for (int r = 0; r < 4; ++r) {
            const int rid = i * 4 + r;
            float bv_ = csq4[0] - 2.0f * acc[i][0][r];
            int   bi_ = cb + wn * 64 + ln15;
#pragma unroll
            for (int j = 1; j < 4; ++j) {
                const float s = csq4[j] - 2.0f * acc[i][j][r];
                const int   c = cb + wn * 64 + j * 16 + ln15;
                if (s < bv_) { bv_ = s; bi_ = c; }
            }
            bval[rid] = bv_; bidx[rid] = bi_;
        }
#pragma unroll
    for (int off = 1; off < 16; off <<= 1) {
#pragma unroll
        for (int rid = 0; rid < 16; ++rid) {
            const float ov = __shfl_xor(bval[rid], off, 64);
            const int   oi = __shfl_xor(bidx[rid], off, 64);
            if (ov < bval[rid] || (ov == bval[rid] && oi < bidx[rid])) {
                bval[rid] = ov; bidx[rid] = oi;
            }
        }
    }

    __syncthreads();
    float* vtab = (float*)&lds[0];
    int*   itab = (int*)&lds[256];
    if (ln15 == 0) {
#pragma unroll
        for (int i = 0; i < 4; ++i)
#pragma unroll
            for (int r = 0; r < 4; ++r) {
                const int row = wm * 64 + i * 16 + quad * 4 + r;
                vtab[row * 2 + wn] = bval[i * 4 + r];
                itab[row * 2 + wn] = bidx[i * 4 + r];
            }
    }
    __syncthreads();
    if (tid < 128) {
        float v0 = vtab[tid * 2]; int i0 = itab[tid * 2];
        const float v1 = vtab[tid * 2 + 1]; const int i1 = itab[tid * 2 + 1];
        if (v1 < v0 || (v1 == v0 && i1 < i0)) { v0 = v1; i0 = i1; }
        const unsigned b   = __float_as_uint(v0);
        const unsigned key = (b & 0x80000000u) ? ~b : (b | 0x80000000u);
        const unsigned long long pk =
            ((unsigned long long)key << 32) | (unsigned long long)(unsigned)i0;
        atomicMin(&ws64[tbase + tid], pk);
    }
}

__global__ __launch_bounds__(256)
void unpack_kernel(const unsigned long long* __restrict__ w, int* __restrict__ out) {
    const int i = blockIdx.x * 256 + threadIdx.x;
    out[i] = (int)(unsigned)(w[i] & 0xFFFFFFFFull);
}

extern "C" void kernel_launch(void* const* d_in, const int* in_sizes, int n_in,
                              void* d_out, int out_size, void* d_ws, size_t ws_size,
                              hipStream_t stream) {
    const float* embed   = (const float*)d_in[0];   // [32768][768] fp32
    const float* centers = (const float*)d_in[1];   // [2048][768] fp32
    int* out = (int*)d_out;                         // [32768] int32

    if (ws_size >= WS_NEED) {
        uint4* Ap = (uint4*)((char*)d_ws + WS_APACK);
        uint4* Bp = (uint4*)((char*)d_ws + WS_BPACK);
        float* csq   = (float*)((char*)d_ws + WS_CSQ);
        uint2* slots = (uint2*)((char*)d_ws + WS_SLOT);
        fragpack_kernel<<<(NA_UNITS + NB_UNITS + NN) / 4, 256, 0, stream>>>(
            embed, centers, Ap, Bp, csq);
        gemm_pack_kernel<<<(MM / 128) * (NN / 128), 256, 0, stream>>>(
            Ap, Bp, csq, slots);
        slot_reduce_kernel<<<MM / 256, 256, 0, stream>>>(slots, out);
    } else {
        unsigned long long* ws64 = (unsigned long long*)d_ws;
        float* csq = (float*)((char*)d_ws + (size_t)MM * 8);
        init_ws_kernel<<<MM / 256, 256, 0, stream>>>(ws64);
        csq_kernel<<<NN, 64, 0, stream>>>(centers, csq);
        argmin_mfma_kernel<<<dim3(MM / 128, NN / 128), 256, 0, stream>>>(
            embed, centers, csq, ws64);
        unpack_kernel<<<MM / 256, 256, 0, stream>>>(ws64, out);
    }
}

// Round 5
// 425.631 us; speedup vs baseline: 1.0424x; 1.0424x over previous
//
#include <hip/hip_runtime.h>

// argmin_c ||x-c|| == argmin_c (||c||^2 - 2 x.c). Cross-term via 3 f16 MFMA
// GEMMs (exact hi/lo split of fp32, lo*lo dropped ~2^-22 rel).
// Round 12: break the MFMA dependency chain. Evidence: three different
// memory structures (register-direct 52%, 256^2-LDS 41%, 128^2-LDS 48%)
// all pin MfmaUtil ~50% at 2 waves/SIMD -> issue-side cap, not memory.
// Every version chained acc[i][j] = MF thrice back-to-back (dependency
// distance 1); if dependent-issue latency ~4x the 4.85cyc interval, one
// wave issues at 25% duty -> 2 waves = ~50%. Fix: term-major order
// hh(j0..3), hl(j0..3), lh(j0..3) -> distance 4 (~19 cyc of independent
// issues) per chain. Per-acc-element order (hh,hl,lh; kt ascending) is
// UNCHANGED -> bit-identical scores -> identical argmin. All else = R11.
typedef __fp16 f16x2 __attribute__((ext_vector_type(2)));
typedef __fp16 f16x8 __attribute__((ext_vector_type(8)));
typedef float f32x4 __attribute__((ext_vector_type(4)));

constexpr int MM = 32768;   // B*T tokens
constexpr int NN = 2048;    // clusters
constexpr int KK = 768;     // dim
constexpr int NKT = KK / 32;          // 24 k-tiles
constexpr int NA_UNITS = (MM / 16) * NKT;   // 49152 A (mt,kt) wave-tasks
constexpr int NB_UNITS = (NN / 16) * NKT;   //  3072 B (nt,kt) wave-tasks

// Workspace layout (bytes). Apack: [mt][kt][part] 1KB units; Bpack same.
constexpr size_t WS_APACK = 0;
constexpr size_t WS_BPACK = WS_APACK + (size_t)MM * KK * 4;  // 100663296
constexpr size_t WS_CSQ   = WS_BPACK + (size_t)NN * KK * 4;  // 106954752
constexpr size_t WS_SLOT  = WS_CSQ + (size_t)NN * 4;         // 106962944
constexpr size_t WS_NEED  = WS_SLOT + (size_t)MM * 16 * 8;   // 111157248

__device__ __forceinline__ unsigned bc(f16x2 h) {
    return __builtin_bit_cast(unsigned, h);
}

// ---------------- fast path ----------------

// One wave packs one (tile16, ktile32, {hi,lo}) pair: reads 16 rows x 128B of
// fp32, writes two contiguous 1KB units in fragment order
// (byte off = (quad*16 + ln15)*16 holds elements m=ln15, k=quad*8..+7).
// Tail tasks (task >= NA+NB) compute csq: one wave per cluster row.
__global__ __launch_bounds__(256)
void fragpack_kernel(const float* __restrict__ A, const float* __restrict__ Bc,
                     uint4* __restrict__ Ap, uint4* __restrict__ Bp,
                     float* __restrict__ csq) {
    const int task = blockIdx.x * 4 + (threadIdx.x >> 6);
    const int lane = threadIdx.x & 63;

    if (task >= NA_UNITS + NB_UNITS) {          // csq tail: wave-uniform branch
        const int cl = task - (NA_UNITS + NB_UNITS);
        const float4* row = reinterpret_cast<const float4*>(Bc + (size_t)cl * KK);
        float s = 0.f;
#pragma unroll
        for (int w = 0; w < KK / (4 * 64); ++w) {
            float4 v = row[w * 64 + lane];
            s = fmaf(v.x, v.x, s); s = fmaf(v.y, v.y, s);
            s = fmaf(v.z, v.z, s); s = fmaf(v.w, v.w, s);
        }
#pragma unroll
        for (int off = 32; off > 0; off >>= 1) s += __shfl_xor(s, off, 64);
        if (lane == 0) csq[cl] = s;
        return;
    }

    const int ln15 = lane & 15;
    const int quad = lane >> 4;

    const bool isB = task >= NA_UNITS;
    const int t = isB ? task - NA_UNITS : task;
    const int tile = t / NKT, kt = t % NKT;
    const float* src = (isB ? Bc : A) + (size_t)(tile * 16 + ln15) * KK + kt * 32 + quad * 8;
    uint4* dst = (isB ? Bp : Ap) + (size_t)t * 128 + lane;   // 2 units = 128 uint4

    const float4 v0 = *(const float4*)(src);
    const float4 v1 = *(const float4*)(src + 4);
    f16x2 h0 = __builtin_amdgcn_cvt_pkrtz(v0.x, v0.y);
    f16x2 h1 = __builtin_amdgcn_cvt_pkrtz(v0.z, v0.w);
    f16x2 h2 = __builtin_amdgcn_cvt_pkrtz(v1.x, v1.y);
    f16x2 h3 = __builtin_amdgcn_cvt_pkrtz(v1.z, v1.w);
    f16x2 l0 = __builtin_amdgcn_cvt_pkrtz(v0.x-(float)h0[0], v0.y-(float)h0[1]);
    f16x2 l1 = __builtin_amdgcn_cvt_pkrtz(v0.z-(float)h1[0], v0.w-(float)h1[1]);
    f16x2 l2 = __builtin_amdgcn_cvt_pkrtz(v1.x-(float)h2[0], v1.y-(float)h2[1]);
    f16x2 l3 = __builtin_amdgcn_cvt_pkrtz(v1.z-(float)h3[0], v1.w-(float)h3[1]);
    uint4 hv = {bc(h0), bc(h1), bc(h2), bc(h3)};
    uint4 lv = {bc(l0), bc(l1), bc(l2), bc(l3)};
    dst[0]  = hv;
    dst[64] = lv;
}

__global__ __launch_bounds__(64)
void csq_kernel(const float* __restrict__ cc, float* __restrict__ csq) {
    const int cl = blockIdx.x;
    const int lane = threadIdx.x;
    const float4* row = reinterpret_cast<const float4*>(cc + (size_t)cl * KK);
    float s = 0.f;
#pragma unroll
    for (int w = 0; w < KK / (4 * 64); ++w) {
        float4 v = row[w * 64 + lane];
        s = fmaf(v.x, v.x, s); s = fmaf(v.y, v.y, s);
        s = fmaf(v.z, v.z, s); s = fmaf(v.w, v.w, s);
    }
#pragma unroll
    for (int off = 32; off > 0; off >>= 1) s += __shfl_xor(s, off, 64);
    if (lane == 0) csq[cl] = s;
}

#define MF2(a, b, c) __builtin_amdgcn_mfma_f32_16x16x32_f16(a, b, c, 0, 0, 0)
#define DSB() __builtin_amdgcn_sched_barrier(0)

// gemm: 128x128 tile per 256-thread block (4 waves 2Mx2N, wave tile 64x64).
// LDS per buffer (2048 uint4 = 32KB): A units (mtile*2+part)*64, mtile 0..7;
// B units (16 + ntile*2+part)*64. Buf1 at +2048. Two buffers = 64KB ->
// 2 blocks/CU co-resident.
__global__ __launch_bounds__(256, 2)
void gemm_pack_kernel(const uint4* __restrict__ Ap, const uint4* __restrict__ Bp,
                      const float* __restrict__ csq, uint2* __restrict__ slots) {
    __shared__ uint4 ldsq[4096];   // 64 KiB

    // XCD swizzle (round-7 proven): 16 gx-blocks sharing an A tile land on one
    // XCD consecutively -> A panel (393KB) L2-resident; B streams from L3.
    const int b   = blockIdx.x;           // 0..4095
    const int xcd = b & 7;
    const int s   = b >> 3;               // 0..511
    const int gx  = s & 15;               // n-block 0..15
    const int gy  = xcd + ((s >> 4) << 3);   // m-block 0..255

    const int tid  = threadIdx.x;
    const int lane = tid & 63;
    const int ln15 = lane & 15;
    const int quad = lane >> 4;
    const int wave = tid >> 6;            // 0..3
    const int wm   = wave >> 1;           // 0..1
    const int wn   = wave & 1;            // 0..1
    const int tbase = gy * 128;
    const int cb    = gx * 128;

    // Per-wave staging sources: units u = wave*8 + q, q=0..7 (32 units total).
    // u<16 -> A unit (mtile=u>>1, part=u&1); else B unit.
    const uint4* sp[8];
#pragma unroll
    for (int q = 0; q < 8; ++q) {
        const int u = wave * 8 + q;
        const bool isA = u < 16;
        const int v = isA ? u : u - 16;
        const int tile = (isA ? gy * 8 : gx * 8) + (v >> 1);
        const int part = v & 1;
        sp[q] = (isA ? Ap : Bp) + (size_t)tile * NKT * 128 + part * 64 + lane;
    }

#define STAGE2(kt_, bufq_, q_) {                                              \
    _Pragma("unroll")                                                         \
    for (int qq = (q_); qq < (q_) + 2; ++qq)                                  \
        __builtin_amdgcn_global_load_lds(                                     \
            (const __attribute__((address_space(1))) unsigned int*)(sp[qq] + (kt_) * 128), \
            (__attribute__((address_space(3))) unsigned int*)&ldsq[(bufq_) + (wave * 8 + qq) * 64], \
            16, 0, 0); }

    f32x4 acc[4][4];
#pragma unroll
    for (int i = 0; i < 4; ++i)
#pragma unroll
        for (int j = 0; j < 4; ++j) { f32x4 z = {0.f,0.f,0.f,0.f}; acc[i][j] = z; }

    f16x8 Bh[4], Bl[4];
    f16x8 Ah[2], Al[2];

#define RD_B(bufq_) {                                                         \
    _Pragma("unroll")                                                         \
    for (int j = 0; j < 4; ++j) {                                             \
        const int nu = 16 + (wn * 4 + j) * 2;                                 \
        Bh[j] = *(const f16x8*)&ldsq[(bufq_) + nu * 64 + lane];               \
        Bl[j] = *(const f16x8*)&ldsq[(bufq_) + (nu + 1) * 64 + lane];         \
    } }

#define RD_A(bufq_, i_, s_) {                                                 \
    const int au = (wm * 4 + (i_)) * 2;                                       \
    Ah[s_] = *(const f16x8*)&ldsq[(bufq_) + au * 64 + lane];                  \
    Al[s_] = *(const f16x8*)&ldsq[(bufq_) + (au + 1) * 64 + lane]; }

// Term-major: each j-sweep touches 4 different accumulators -> dependency
// distance 4 (was 1). Per-element accumulation order still hh, hl, lh.
#define MFMA_I(i_, s_) {                                                      \
    __builtin_amdgcn_s_setprio(1);                                            \
    _Pragma("unroll")                                                         \
    for (int j = 0; j < 4; ++j) acc[i_][j] = MF2(Ah[s_], Bh[j], acc[i_][j]);  \
    _Pragma("unroll")                                                         \
    for (int j = 0; j < 4; ++j) acc[i_][j] = MF2(Ah[s_], Bl[j], acc[i_][j]);  \
    _Pragma("unroll")                                                         \
    for (int j = 0; j < 4; ++j) acc[i_][j] = MF2(Al[s_], Bh[j], acc[i_][j]);  \
    __builtin_amdgcn_s_setprio(0); }

    // Prologue: stage kt=0 fully into buf0.
    STAGE2(0, 0, 0) STAGE2(0, 0, 2) STAGE2(0, 0, 4) STAGE2(0, 0, 6)

#pragma unroll 1
    for (int kt = 0; kt < NKT; ++kt) {
        const int bufq = (kt & 1) ? 2048 : 0;
        const int nxt  = bufq ^ 2048;
        const bool sn  = (kt + 1 < NKT);

        if (sn) {
            STAGE2(kt + 1, nxt, 0)
            asm volatile("s_waitcnt vmcnt(2)" ::: "memory");
        } else {
            asm volatile("s_waitcnt vmcnt(0)" ::: "memory");
        }
        DSB(); __builtin_amdgcn_s_barrier(); DSB();   // buf[kt] fully staged

        RD_B(bufq)
        RD_A(bufq, 0, 0)
        DSB();
        RD_A(bufq, 1, 1)
        if (sn) STAGE2(kt + 1, nxt, 2)
        DSB();
        MFMA_I(0, 0)
        DSB();
        RD_A(bufq, 2, 0)
        if (sn) STAGE2(kt + 1, nxt, 4)
        DSB();
        MFMA_I(1, 1)
        DSB();
        RD_A(bufq, 3, 1)
        if (sn) STAGE2(kt + 1, nxt, 6)
        DSB();
        MFMA_I(2, 0)
        DSB();
        MFMA_I(3, 1)
        DSB(); __builtin_amdgcn_s_barrier(); DSB();   // release buf[kt]
    }

    // Epilogue: score = csq - 2*dot; C/D layout col=lane&15, row=quad*4+reg.
    float csq4[4];
#pragma unroll
    for (int j = 0; j < 4; ++j) csq4[j] = csq[cb + wn * 64 + j * 16 + ln15];

    float bval[16]; int bidx[16];
#pragma unroll
    for (int i = 0; i < 4; ++i)
#pragma unroll
        for (int r = 0; r < 4; ++r) {
            const int rid = i * 4 + r;
            float bv_ = csq4[0] - 2.0f * acc[i][0][r];
            int   bi_ = cb + wn * 64 + ln15;
#pragma unroll
            for (int j = 1; j < 4; ++j) {
                const float s2 = csq4[j] - 2.0f * acc[i][j][r];
                const int   c = cb + wn * 64 + j * 16 + ln15;
                if (s2 < bv_) { bv_ = s2; bi_ = c; }   // ascending c, strict <
            }
            bval[rid] = bv_; bidx[rid] = bi_;
        }
#pragma unroll
    for (int off = 1; off < 16; off <<= 1) {
#pragma unroll
        for (int rid = 0; rid < 16; ++rid) {
            const float ov = __shfl_xor(bval[rid], off, 64);
            const int   oi = __shfl_xor(bidx[rid], off, 64);
            if (ov < bval[rid] || (ov == bval[rid] && oi < bidx[rid])) {
                bval[rid] = ov; bidx[rid] = oi;
            }
        }
    }

    __syncthreads();                       // all LDS reads done; reuse for tabs
    float* vtab = (float*)&ldsq[0];        // [128 rows][2 wn]
    int*   itab = (int*)&ldsq[64];
    if (ln15 == 0) {
#pragma unroll
        for (int i = 0; i < 4; ++i)
#pragma unroll
            for (int r = 0; r < 4; ++r) {
                const int row = wm * 64 + i * 16 + quad * 4 + r;
                vtab[row * 2 + wn] = bval[i * 4 + r];
                itab[row * 2 + wn] = bidx[i * 4 + r];
            }
    }
    __syncthreads();
    if (tid < 128) {
        float v0 = vtab[tid * 2]; int i0 = itab[tid * 2];
        const float v1 = vtab[tid * 2 + 1]; const int i1 = itab[tid * 2 + 1];
        if (v1 < v0 || (v1 == v0 && i1 < i0)) { v0 = v1; i0 = i1; }
        uint2 e; e.x = __float_as_uint(v0); e.y = (unsigned)i0;
        slots[(size_t)(tbase + tid) * 16 + gx] = e;
    }
}

__global__ __launch_bounds__(256)
void slot_reduce_kernel(const uint2* __restrict__ slots, int* __restrict__ out) {
    const int t = blockIdx.x * 256 + threadIdx.x;
    const uint2* s = slots + (size_t)t * 16;
    float bv = __uint_as_float(s[0].x); int bi = (int)s[0].y;
#pragma unroll
    for (int j = 1; j < 16; ++j) {
        const uint2 e = s[j];
        const float v = __uint_as_float(e.x);
        if (v < bv || (v == bv && (int)e.y < bi)) { bv = v; bi = (int)e.y; }
    }
    out[t] = bi;
}

// ---------------- round-3 fallback (proven, used only if ws too small) ------

__global__ __launch_bounds__(256)
void init_ws_kernel(unsigned long long* __restrict__ w) {
    w[blockIdx.x * 256 + threadIdx.x] = 0xFFFFFFFFFFFFFFFFull;
}

__global__ __launch_bounds__(256, 2)
void argmin_mfma_kernel(const float* __restrict__ A, const float* __restrict__ Bc,
                        const float* __restrict__ csq,
                        unsigned long long* __restrict__ ws64) {
    __shared__ unsigned lds[4 * 128 * 20];
    constexpr int AH = 0, AL = 2560, BH = 5120;

    const int tid  = threadIdx.x;
    const int lane = tid & 63;
    const int ln15 = lane & 15;
    const int quad = lane >> 4;
    const int wave = tid >> 6;
    const int wm = wave >> 1, wn = wave & 1;
    const int tbase = blockIdx.x * 128;
    const int cb    = blockIdx.y * 128;

    const int sr  = tid >> 1;
    const int skh = tid & 1;
    const float* gA = A  + (size_t)(tbase + sr) * KK + skh * 16;
    const float* gB = Bc + (size_t)(cb   + sr) * KK + skh * 16;
    const int wword = sr * 20 + skh * 8;

    f32x4 acc[4][4];
#pragma unroll
    for (int i = 0; i < 4; ++i)
#pragma unroll
        for (int j = 0; j < 4; ++j) { f32x4 z = {0.f,0.f,0.f,0.f}; acc[i][j] = z; }

    float4 av[4], bv[4];
#pragma unroll
    for (int p = 0; p < 4; ++p) {
        av[p] = *(const float4*)(gA + p * 4);
        bv[p] = *(const float4*)(gB + p * 4);
    }

    int aw[4], bw[4];
#pragma unroll
    for (int i = 0; i < 4; ++i) {
        aw[i] = AH + (wm * 64 + i * 16 + ln15) * 20 + quad * 4;
        bw[i] = BH + (wn * 64 + i * 16 + ln15) * 20 + quad * 4;
    }

    for (int k0 = 0; k0 < KK; k0 += 32) {
        __syncthreads();
#pragma unroll
        for (int h = 0; h < 2; ++h) {
            float4 v0 = av[2*h], v1 = av[2*h+1];
            f16x2 h00 = __builtin_amdgcn_cvt_pkrtz(v0.x, v0.y);
            f16x2 h01 = __builtin_amdgcn_cvt_pkrtz(v0.z, v0.w);
            f16x2 h10 = __builtin_amdgcn_cvt_pkrtz(v1.x, v1.y);
            f16x2 h11 = __builtin_amdgcn_cvt_pkrtz(v1.z, v1.w);
            f16x2 l00 = __builtin_amdgcn_cvt_pkrtz(v0.x-(float)h00[0], v0.y-(float)h00[1]);
            f16x2 l01 = __builtin_amdgcn_cvt_pkrtz(v0.z-(float)h01[0], v0.w-(float)h01[1]);
            f16x2 l10 = __builtin_amdgcn_cvt_pkrtz(v1.x-(float)h10[0], v1.y-(float)h10[1]);
            f16x2 l11 = __builtin_amdgcn_cvt_pkrtz(v1.z-(float)h11[0], v1.w-(float)h11[1]);
            uint4 hv = {bc(h00), bc(h01), bc(h10), bc(h11)};
            uint4 lv = {bc(l00), bc(l01), bc(l10), bc(l11)};
            *(uint4*)&lds[AH + wword + 4*h] = hv;
            *(uint4*)&lds[AL + wword + 4*h] = lv;

            float4 w0 = bv[2*h], w1 = bv[2*h+1];
            f16x2 g00 = __builtin_amdgcn_cvt_pkrtz(w0.x, w0.y);
            f16x2 g01 = __builtin_amdgcn_cvt_pkrtz(w0.z, w0.w);
            f16x2 g10 = __builtin_amdgcn_cvt_pkrtz(w1.x, w1.y);
            f16x2 g11 = __builtin_amdgcn_cvt_pkrtz(w1.z, w1.w);
            f16x2 m00 = __builtin_amdgcn_cvt_pkrtz(w0.x-(float)g00[0], w0.y-(float)g00[1]);
            f16x2 m01 = __builtin_amdgcn_cvt_pkrtz(w0.z-(float)g01[0], w0.w-(float)g01[1]);
            f16x2 m10 = __builtin_amdgcn_cvt_pkrtz(w1.x-(float)g10[0], w1.y-(float)g10[1]);
            f16x2 m11 = __builtin_amdgcn_cvt_pkrtz(w1.z-(float)g11[0], w1.w-(float)g11[1]);
            uint4 gv = {bc(g00), bc(g01), bc(g10), bc(g11)};
            uint4 mv = {bc(m00), bc(m01), bc(m10), bc(m11)};
            *(uint4*)&lds[BH + wword + 4*h]        = gv;
            *(uint4*)&lds[BH + 2560 + wword + 4*h] = mv;
        }
        __syncthreads();

        const int kn = k0 + 32;
        if (kn < KK) {
#pragma unroll
            for (int p = 0; p < 4; ++p) {
                av[p] = *(const float4*)(gA + kn + p * 4);
                bv[p] = *(const float4*)(gB + kn + p * 4);
            }
        }

        f16x8 a_h[4], a_l[4], b_h[4], b_l[4];
#pragma unroll
        for (int i = 0; i < 4; ++i) {
            a_h[i] = *(const f16x8*)&lds[aw[i]];
            a_l[i] = *(const f16x8*)&lds[aw[i] + 2560];
            b_h[i] = *(const f16x8*)&lds[bw[i]];
            b_l[i] = *(const f16x8*)&lds[bw[i] + 2560];
        }
#pragma unroll
        for (int i = 0; i < 4; ++i)
#pragma unroll
            for (int j = 0; j < 4; ++j) {
                acc[i][j] = __builtin_amdgcn_mfma_f32_16x16x32_f16(a_h[i], b_h[j], acc[i][j], 0, 0, 0);
                acc[i][j] = __builtin_amdgcn_mfma_f32_16x16x32_f16(a_h[i], b_l[j], acc[i][j], 0, 0, 0);
                acc[i][j] = __builtin_amdgcn_mfma_f32_16x16x32_f16(a_l[i], b_h[j], acc[i][j], 0, 0, 0);
            }
    }

    float csq4[4];
#pragma unroll
    for (int j = 0; j < 4; ++j) csq4[j] = csq[cb + wn * 64 + j * 16 + ln15];

    float bval[16]; int bidx[16];
#pragma unroll
    for (int i = 0; i < 4; ++i)
#pragma unroll
        for (int r = 0; r < 4; ++r) {
            const int rid = i * 4 + r;
            float bv_ = csq4[0] - 2.0f * acc[i][0][r];
            int   bi_ = cb + wn * 64 + ln15;
#pragma unroll
            for (int j = 1; j < 4; ++j) {
                const float s = csq4[j] - 2.0f * acc[i][j][r];
                const int   c = cb + wn * 64 + j * 16 + ln15;
                if (s < bv_) { bv_ = s; bi_ = c; }
            }
            bval[rid] = bv_; bidx[rid] = bi_;
        }
#pragma unroll
    for (int off = 1; off < 16; off <<= 1) {
#pragma unroll
        for (int rid = 0; rid < 16; ++rid) {
            const float ov = __shfl_xor(bval[rid], off, 64);
            const int   oi = __shfl_xor(bidx[rid], off, 64);
            if (ov < bval[rid] || (ov == bval[rid] && oi < bidx[rid])) {
                bval[rid] = ov; bidx[rid] = oi;
            }
        }
    }

    __syncthreads();
    float* vtab = (float*)&lds[0];
    int*   itab = (int*)&lds[256];
    if (ln15 == 0) {
#pragma unroll
        for (int i = 0; i < 4; ++i)
#pragma unroll
            for (int r = 0; r < 4; ++r) {
                const int row = wm * 64 + i * 16 + quad * 4 + r;
                vtab[row * 2 + wn] = bval[i * 4 + r];
                itab[row * 2 + wn] = bidx[i * 4 + r];
            }
    }
    __syncthreads();
    if (tid < 128) {
        float v0 = vtab[tid * 2]; int i0 = itab[tid * 2];
        const float v1 = vtab[tid * 2 + 1]; const int i1 = itab[tid * 2 + 1];
        if (v1 < v0 || (v1 == v0 && i1 < i0)) { v0 = v1; i0 = i1; }
        const unsigned b   = __float_as_uint(v0);
        const unsigned key = (b & 0x80000000u) ? ~b : (b | 0x80000000u);
        const unsigned long long pk =
            ((unsigned long long)key << 32) | (unsigned long long)(unsigned)i0;
        atomicMin(&ws64[tbase + tid], pk);
    }
}

__global__ __launch_bounds__(256)
void unpack_kernel(const unsigned long long* __restrict__ w, int* __restrict__ out) {
    const int i = blockIdx.x * 256 + threadIdx.x;
    out[i] = (int)(unsigned)(w[i] & 0xFFFFFFFFull);
}

extern "C" void kernel_launch(void* const* d_in, const int* in_sizes, int n_in,
                              void* d_out, int out_size, void* d_ws, size_t ws_size,
                              hipStream_t stream) {
    const float* embed   = (const float*)d_in[0];   // [32768][768] fp32
    const float* centers = (const float*)d_in[1];   // [2048][768] fp32
    int* out = (int*)d_out;                         // [32768] int32

    if (ws_size >= WS_NEED) {
        uint4* Ap = (uint4*)((char*)d_ws + WS_APACK);
        uint4* Bp = (uint4*)((char*)d_ws + WS_BPACK);
        float* csq   = (float*)((char*)d_ws + WS_CSQ);
        uint2* slots = (uint2*)((char*)d_ws + WS_SLOT);
        fragpack_kernel<<<(NA_UNITS + NB_UNITS + NN) / 4, 256, 0, stream>>>(
            embed, centers, Ap, Bp, csq);
        gemm_pack_kernel<<<(MM / 128) * (NN / 128), 256, 0, stream>>>(
            Ap, Bp, csq, slots);
        slot_reduce_kernel<<<MM / 256, 256, 0, stream>>>(slots, out);
    } else {
        unsigned long long* ws64 = (unsigned long long*)d_ws;
        float* csq = (float*)((char*)d_ws + (size_t)MM * 8);
        init_ws_kernel<<<MM / 256, 256, 0, stream>>>(ws64);
        csq_kernel<<<NN, 64, 0, stream>>>(centers, csq);
        argmin_mfma_kernel<<<dim3(MM / 128, NN / 128), 256, 0, stream>>>(
            embed, centers, csq, ws64);
        unpack_kernel<<<MM / 256, 256, 0, stream>>>(ws64, out);
    }
}